// Round 1
// baseline (110.562 us; speedup 1.0000x reference)
//
#include <hip/hip_runtime.h>

#define HH 256
#define WW 256
#define TT 32
#define TI 16

struct alignas(16) F4 { float x, y, z, w; };
__device__ inline F4 operator+(F4 a, F4 b) { return {a.x+b.x, a.y+b.y, a.z+b.z, a.w+b.w}; }
__device__ inline F4 operator-(F4 a, F4 b) { return {a.x-b.x, a.y-b.y, a.z-b.z, a.w-b.w}; }
__device__ inline F4 operator*(F4 a, F4 b) { return {a.x*b.x, a.y*b.y, a.z*b.z, a.w*b.w}; }
__device__ inline F4 operator*(F4 a, float s) { return {a.x*s, a.y*s, a.z*s, a.w*s}; }
__device__ inline F4 operator*(float s, F4 a) { return {a.x*s, a.y*s, a.z*s, a.w*s}; }

__global__ __launch_bounds__(1024) void pil_main(const float* __restrict__ p,
                                                 const float* __restrict__ Kf,
                                                 double* __restrict__ ws) {
  __shared__ float sP[TI + 4][WW];
  __shared__ float sK[TI + 2][WW];
  __shared__ double redN[16];
  __shared__ int redD[16];

  const int tile = blockIdx.x;
  const int b = blockIdx.y;
  const int i0 = tile * TI;
  const int tid = threadIdx.x;
  const int r = tid >> 6;         // row within tile (wave-uniform)
  const int g = tid & 63;         // column group
  const int j0 = g << 2;          // first of 4 consecutive cols
  const int i = i0 + r;           // global row

  const float i2hx = 0.02f;       // 1/(2*25)
  const float i2hy = 0.01f;       // 1/(2*50)
  const float Sc = 2e-4f;

  // per-point rolling state (4 cols per thread)
  float cm2[4] = {0, 0, 0, 0}, cm1[4] = {0, 0, 0, 0};
  float dkA[4] = {0, 0, 0, 0}, dkB[4] = {0, 0, 0, 0};
  float mA[4] = {0, 0, 0, 0}, mB[4] = {0, 0, 0, 0};
  double accN = 0.0;
  int accD = 0;

  const size_t bbase = (size_t)b * TT * (HH * WW);

#pragma unroll 1
  for (int t = 0; t < TT; ++t) {
    __syncthreads();
    // stage p rows [i0-2, i0+17], K rows [i0-1, i0+16] (clamped to domain)
    const float* pl = p + bbase + (size_t)t * (HH * WW);
    for (int idx = tid; idx < (TI + 4) * 64; idx += 1024) {
      int lr = idx >> 6, c4 = (idx & 63) << 2;
      int gr = i0 - 2 + lr;
      if (gr >= 0 && gr < HH)
        *reinterpret_cast<F4*>(&sP[lr][c4]) =
            *reinterpret_cast<const F4*>(pl + gr * WW + c4);
    }
    const float* kl = Kf + bbase + (size_t)t * (HH * WW);
    for (int idx = tid; idx < (TI + 2) * 64; idx += 1024) {
      int lr = idx >> 6, c4 = (idx & 63) << 2;
      int gr = i0 - 1 + lr;
      if (gr >= 0 && gr < HH)
        *reinterpret_cast<F4*>(&sK[lr][c4]) =
            *reinterpret_cast<const F4*>(kl + gr * WW + c4);
    }
    __syncthreads();

    auto LP = [&](int gr) -> F4 {
      return *reinterpret_cast<const F4*>(&sP[gr - i0 + 2][j0]);
    };
    auto LK = [&](int gr) -> F4 {
      return *reinterpret_cast<const F4*>(&sK[gr - i0 + 1][j0]);
    };

    // ---- row-direction terms (branches wave-uniform: wave == one row) ----
    F4 pdx4, t14, pdxx4, kdx4, kc0v, pc0v;
    if (i >= 2 && i <= HH - 3) {
      F4 r0 = LP(i - 2), r1 = LP(i - 1), r2 = LP(i), r3 = LP(i + 1), r4 = LP(i + 2);
      F4 km = LK(i - 1), kc = LK(i), kp = LK(i + 1);
      F4 gm = (r2 - r0) * i2hx;
      F4 gp = (r4 - r2) * i2hx;
      pdx4 = (r3 - r1) * i2hx;
      t14 = (kp * gp - km * gm) * i2hx;
      pdxx4 = (gp - gm) * i2hx;
      kdx4 = (kp - km) * i2hx;
      kc0v = kc; pc0v = r2;
    } else if (i == 0) {
      F4 a0 = LP(0), a1 = LP(1), a2 = LP(2), a3 = LP(3);
      F4 k0 = LK(0), k1 = LK(1), k2 = LK(2);
      F4 g0 = (4.0f * a1 - 3.0f * a0 - a2) * i2hx;
      F4 g1 = (a2 - a0) * i2hx;
      F4 g2 = (a3 - a1) * i2hx;
      pdx4 = g0;
      t14 = (4.0f * (k1 * g1) - 3.0f * (k0 * g0) - k2 * g2) * i2hx;
      pdxx4 = (4.0f * g1 - 3.0f * g0 - g2) * i2hx;
      kdx4 = (4.0f * k1 - 3.0f * k0 - k2) * i2hx;
      kc0v = k0; pc0v = a0;
    } else if (i == 1) {
      F4 a0 = LP(0), a1 = LP(1), a2 = LP(2), a3 = LP(3);
      F4 k0 = LK(0), k2 = LK(2), k1 = LK(1);
      F4 gm = (4.0f * a1 - 3.0f * a0 - a2) * i2hx;  // g(0) edge
      F4 gp = (a3 - a1) * i2hx;                      // g(2)
      pdx4 = (a2 - a0) * i2hx;
      t14 = (k2 * gp - k0 * gm) * i2hx;
      pdxx4 = (gp - gm) * i2hx;
      kdx4 = (k2 - k0) * i2hx;
      kc0v = k1; pc0v = a1;
    } else if (i == HH - 2) {  // 254
      F4 a0 = LP(HH - 4), a1 = LP(HH - 3), a2 = LP(HH - 2), a3 = LP(HH - 1);
      F4 k3 = LK(HH - 3), kcen = LK(HH - 2), kN = LK(HH - 1);
      F4 gm = (a2 - a0) * i2hx;                       // g(253)
      F4 gp = (3.0f * a3 - 4.0f * a2 + a1) * i2hx;    // g(255) edge
      pdx4 = (a3 - a1) * i2hx;
      t14 = (kN * gp - k3 * gm) * i2hx;
      pdxx4 = (gp - gm) * i2hx;
      kdx4 = (kN - k3) * i2hx;
      kc0v = kcen; pc0v = a2;
    } else {  // i == 255
      F4 a0 = LP(HH - 4), a1 = LP(HH - 3), a2 = LP(HH - 2), a3 = LP(HH - 1);
      F4 k3 = LK(HH - 3), k4 = LK(HH - 2), kN = LK(HH - 1);
      F4 gm2 = (a2 - a0) * i2hx;                      // g(253)
      F4 gm1 = (a3 - a1) * i2hx;                      // g(254)
      F4 gN = (3.0f * a3 - 4.0f * a2 + a1) * i2hx;    // g(255) edge
      pdx4 = gN;
      t14 = (3.0f * (kN * gN) - 4.0f * (k4 * gm1) + k3 * gm2) * i2hx;
      pdxx4 = (3.0f * gN - 4.0f * gm1 + gm2) * i2hx;
      kdx4 = (3.0f * kN - 4.0f * k4 + k3) * i2hx;
      kc0v = kN; pc0v = a3;
    }

    // ---- column-direction neighborhoods ----
    const int li = i - i0 + 2;
    const int liK = i - i0 + 1;
    const int jL = (j0 >= 4) ? (j0 - 4) : 0;
    const int jR = (j0 + 4 <= WW - 4) ? (j0 + 4) : (WW - 4);
    F4 pLv = *reinterpret_cast<const F4*>(&sP[li][jL]);
    F4 pRv = *reinterpret_cast<const F4*>(&sP[li][jR]);
    F4 kLv = *reinterpret_cast<const F4*>(&sK[liK][jL]);
    F4 kRv = *reinterpret_cast<const F4*>(&sK[liK][jR]);

    float pc[12] = {pLv.x, pLv.y, pLv.z, pLv.w, pc0v.x, pc0v.y, pc0v.z, pc0v.w,
                    pRv.x, pRv.y, pRv.z, pRv.w};
    float kcA[12] = {kLv.x, kLv.y, kLv.z, kLv.w, kc0v.x, kc0v.y, kc0v.z, kc0v.w,
                     kRv.x, kRv.y, kRv.z, kRv.w};
    float pdxa[4] = {pdx4.x, pdx4.y, pdx4.z, pdx4.w};
    float t1a[4] = {t14.x, t14.y, t14.z, t14.w};
    float pdxxa[4] = {pdxx4.x, pdxx4.y, pdxx4.z, pdxx4.w};
    float kdxa[4] = {kdx4.x, kdx4.y, kdx4.z, kdx4.w};

#pragma unroll
    for (int q = 0; q < 4; ++q) {
      const int j = j0 + q;
      float pdy, t2, pdyy, kdy;
      if (j >= 2 && j <= WW - 3) {
        float gm = (pc[4 + q] - pc[2 + q]) * i2hy;   // gy(j-1)
        float gp = (pc[6 + q] - pc[4 + q]) * i2hy;   // gy(j+1)
        pdy = (pc[5 + q] - pc[3 + q]) * i2hy;
        t2 = (kcA[5 + q] * gp - kcA[3 + q] * gm) * i2hy;
        pdyy = (gp - gm) * i2hy;
        kdy = (kcA[5 + q] - kcA[3 + q]) * i2hy;
      } else if (j == 0) {  // q==0, g==0
        float g0 = (4.0f * pc[5] - 3.0f * pc[4] - pc[6]) * i2hy;
        float g1 = (pc[6] - pc[4]) * i2hy;
        float g2 = (pc[7] - pc[5]) * i2hy;
        pdy = g0;
        t2 = (4.0f * (kcA[5] * g1) - 3.0f * (kcA[4] * g0) - kcA[6] * g2) * i2hy;
        pdyy = (4.0f * g1 - 3.0f * g0 - g2) * i2hy;
        kdy = (4.0f * kcA[5] - 3.0f * kcA[4] - kcA[6]) * i2hy;
      } else if (j == 1) {  // q==1, g==0
        float gm = (4.0f * pc[5] - 3.0f * pc[4] - pc[6]) * i2hy;  // gy(0) edge
        float gp = (pc[7] - pc[5]) * i2hy;                         // gy(2)
        pdy = (pc[6] - pc[4]) * i2hy;
        t2 = (kcA[6] * gp - kcA[4] * gm) * i2hy;
        pdyy = (gp - gm) * i2hy;
        kdy = (kcA[6] - kcA[4]) * i2hy;
      } else if (j == WW - 2) {  // 254, q==2, g==63
        float gm = (pc[6] - pc[4]) * i2hy;                         // gy(253)
        float gp = (3.0f * pc[7] - 4.0f * pc[6] + pc[5]) * i2hy;   // gy(255) edge
        pdy = (pc[7] - pc[5]) * i2hy;
        t2 = (kcA[7] * gp - kcA[5] * gm) * i2hy;
        pdyy = (gp - gm) * i2hy;
        kdy = (kcA[7] - kcA[5]) * i2hy;
      } else {  // j == 255, q==3, g==63
        float gm2 = (pc[6] - pc[4]) * i2hy;   // gy(253)
        float gm1 = (pc[7] - pc[5]) * i2hy;   // gy(254)
        float gN = (3.0f * pc[7] - 4.0f * pc[6] + pc[5]) * i2hy;
        pdy = gN;
        t2 = (3.0f * (kcA[7] * gN) - 4.0f * (kcA[6] * gm1) + kcA[5] * gm2) * i2hy;
        pdyy = (3.0f * gN - 4.0f * gm1 + gm2) * i2hy;
        kdy = (3.0f * kcA[7] - 4.0f * kcA[6] + kcA[5]) * i2hy;
      }

      float divk = t1a[q] + t2;
      float divk2 = (pdxxa[q] + pdyy) * kcA[4 + q] + pdxa[q] * kdxa[q] + pdy * kdy;
      float cT = pc[4 + q];
      float m = (fabsf(divk - divk2) < 100.0f) ? 1.0f : 0.0f;

      // deferred time-gradient completion
      if (t >= 2) {
        // finish plane t-1 (interior): p_dt = (c(t) - c(t-2))/2
        float pdt = (cT - cm2[q]) * 0.5f;
        float d = dkB[q] - pdt * Sc;
        accN += (double)(d * d * mB[q]);
        accD += (int)mB[q];
        if (t == 2) {
          // finish plane 0 (edge): p_dt = (-3c0 + 4c1 - c2)/2
          float pdt0 = (4.0f * cm1[q] - 3.0f * cm2[q] - cT) * 0.5f;
          float d0 = dkA[q] - pdt0 * Sc;
          accN += (double)(d0 * d0 * mA[q]);
          accD += (int)mA[q];
        }
      }
      if (t == TT - 1) {
        // finish plane 31 (edge): p_dt = (3c31 - 4c30 + c29)/2
        float pdtN = (3.0f * cT - 4.0f * cm1[q] + cm2[q]) * 0.5f;
        float dN = divk - pdtN * Sc;
        accN += (double)(dN * dN * m);
        accD += (int)m;
      }
      dkA[q] = dkB[q]; mA[q] = mB[q];
      dkB[q] = divk;   mB[q] = m;
      cm2[q] = cm1[q]; cm1[q] = cT;
    }
  }

  // ---- block reduction ----
  for (int off = 32; off > 0; off >>= 1) {
    accN += __shfl_down(accN, off);
    accD += __shfl_down(accD, off);
  }
  const int wid = tid >> 6;
  if ((tid & 63) == 0) { redN[wid] = accN; redD[wid] = accD; }
  __syncthreads();
  if (tid == 0) {
    double n = 0.0; long long dd = 0;
    for (int w = 0; w < 16; ++w) { n += redN[w]; dd += redD[w]; }
    const int slot = b * 16 + tile;
    ws[slot] = n;
    ws[256 + slot] = (double)dd;
  }
}

__global__ void pil_final(const double* __restrict__ ws, float* __restrict__ out) {
  __shared__ double s[16];
  const int tid = threadIdx.x;  // 256 threads: tid = b*16 + tile
  double n = ws[tid];
  double d = ws[256 + tid];
  for (int off = 8; off > 0; off >>= 1) {
    n += __shfl_down(n, off, 16);
    d += __shfl_down(d, off, 16);
  }
  if ((tid & 15) == 0) s[tid >> 4] = n / d;
  __syncthreads();
  if (tid == 0) {
    double acc = 0.0;
    for (int bb = 0; bb < 16; ++bb) acc += s[bb];
    out[0] = (float)(acc / 16.0);
  }
}

extern "C" void kernel_launch(void* const* d_in, const int* in_sizes, int n_in,
                              void* d_out, int out_size, void* d_ws, size_t ws_size,
                              hipStream_t stream) {
  const float* p = (const float*)d_in[0];
  const float* K = (const float*)d_in[1];
  double* ws = (double*)d_ws;
  float* out = (float*)d_out;
  dim3 grid(HH / TI, 16);  // (tiles per plane, batches) = (16, 16)
  pil_main<<<grid, 1024, 0, stream>>>(p, K, ws);
  pil_final<<<1, 256, 0, stream>>>(ws, out);
}

// Round 2
// 83.934 us; speedup vs baseline: 1.3173x; 1.3173x over previous
//
#include <hip/hip_runtime.h>

#define HH 256
#define WW 256
#define TT 32
#define TI 16
#define CHUNK 16
#define PLANE (HH * WW)

struct alignas(16) F4 { float x, y, z, w; };
__device__ inline F4 operator+(F4 a, F4 b) { return {a.x+b.x, a.y+b.y, a.z+b.z, a.w+b.w}; }
__device__ inline F4 operator-(F4 a, F4 b) { return {a.x-b.x, a.y-b.y, a.z-b.z, a.w-b.w}; }
__device__ inline F4 operator*(F4 a, F4 b) { return {a.x*b.x, a.y*b.y, a.z*b.z, a.w*b.w}; }
__device__ inline F4 operator*(F4 a, float s) { return {a.x*s, a.y*s, a.z*s, a.w*s}; }
__device__ inline F4 operator*(float s, F4 a) { return {a.x*s, a.y*s, a.z*s, a.w*s}; }

// async global->LDS, 16B per lane; LDS dest = wave-uniform base + lane*16
__device__ __forceinline__ void gload16(const float* g, float* l) {
  __builtin_amdgcn_global_load_lds(
      (const __attribute__((address_space(1))) void*)g,
      (__attribute__((address_space(3))) void*)l, 16, 0, 0);
}

__global__ __launch_bounds__(1024) void pil_main(const float* __restrict__ p,
                                                 const float* __restrict__ Kf,
                                                 double* __restrict__ ws) {
  __shared__ float sP[2][TI + 4][WW];   // 2 x 20 x 256 x 4B = 40 KB
  __shared__ float sK[2][TI + 2][WW];   // 2 x 18 x 256 x 4B = 36 KB
  __shared__ double redN[16];
  __shared__ int redD[16];

  const int tile = blockIdx.x;
  const int b = blockIdx.y;
  const int chunk = blockIdx.z;
  const int t0 = chunk * CHUNK;
  const int tstart = (chunk == 0) ? 0 : (t0 - 1);
  const int tend = (chunk == 0) ? (t0 + CHUNK) : (TT - 1);
  const int cmplT = (t0 == 0) ? 2 : (t0 + 1);

  const int i0 = tile * TI;
  const int tid = threadIdx.x;
  const int r = tid >> 6;         // row within tile (wave-uniform)
  const int g = tid & 63;         // column group
  const int j0 = g << 2;          // first of 4 consecutive cols
  const int i = i0 + r;           // global row
  const int wid = tid >> 6;
  const int lane = tid & 63;

  const float i2hx = 0.02f;       // 1/(2*25)
  const float i2hy = 0.01f;       // 1/(2*50)
  const float Sc = 2e-4f;

  float cm2[4] = {0, 0, 0, 0}, cm1[4] = {0, 0, 0, 0};
  float dkA[4] = {0, 0, 0, 0}, dkB[4] = {0, 0, 0, 0};
  float mA[4] = {0, 0, 0, 0}, mB[4] = {0, 0, 0, 0};
  double accN = 0.0;
  int accD = 0;

  const size_t bbase = (size_t)b * TT * PLANE;

  // ---- async staging of one time-plane into buffer `buf` ----
  auto stage = [&](int t, int buf, bool doK) {
    const float* pl = p + bbase + (size_t)t * PLANE;
    const int nrows = doK ? (TI + 4) + (TI + 2) : (TI + 4);
    for (int idx = wid; idx < nrows; idx += 16) {
      if (idx < TI + 4) {
        int gr = i0 - 2 + idx;
        if (gr >= 0 && gr < HH)
          gload16(pl + (size_t)gr * WW + (lane << 2), &sP[buf][idx][0]);
      } else {
        int kr = idx - (TI + 4);
        int gr = i0 - 1 + kr;
        if (gr >= 0 && gr < HH)
          gload16(Kf + bbase + (size_t)t * PLANE + (size_t)gr * WW + (lane << 2),
                  &sK[buf][kr][0]);
      }
    }
  };

  // prologue: stage first plane
  stage(tstart, 0, (tstart >= t0) && (tstart < t0 + CHUNK));
  __syncthreads();  // implicit vmcnt(0) drain -> plane resident

#pragma unroll 1
  for (int t = tstart; t <= tend; ++t) {
    const int cur = (t - tstart) & 1;
    float (*sPc)[WW] = sP[cur];
    float (*sKc)[WW] = sK[cur];
    const bool do_divk = (t >= t0) && (t < t0 + CHUNK);

    // issue async loads for next plane into the other buffer
    if (t < tend) {
      const int tn = t + 1;
      stage(tn, cur ^ 1, (tn >= t0) && (tn < t0 + CHUNK));
    }

    const int li = i - i0 + 2;
    const int liK = i - i0 + 1;

    float cTa[4], divka[4] = {0, 0, 0, 0}, ma[4] = {0, 0, 0, 0};
    {
      F4 c4 = *reinterpret_cast<const F4*>(&sPc[li][j0]);
      cTa[0] = c4.x; cTa[1] = c4.y; cTa[2] = c4.z; cTa[3] = c4.w;
    }

    if (do_divk) {
      auto LP = [&](int gr) -> F4 {
        return *reinterpret_cast<const F4*>(&sPc[gr - i0 + 2][j0]);
      };
      auto LK = [&](int gr) -> F4 {
        return *reinterpret_cast<const F4*>(&sKc[gr - i0 + 1][j0]);
      };

      // ---- row-direction terms (branches wave-uniform) ----
      F4 pdx4, t14, pdxx4, kdx4, kc0v, pc0v;
      if (i >= 2 && i <= HH - 3) {
        F4 r0 = LP(i - 2), r1 = LP(i - 1), r2 = LP(i), r3 = LP(i + 1), r4 = LP(i + 2);
        F4 km = LK(i - 1), kc = LK(i), kp = LK(i + 1);
        F4 gm = (r2 - r0) * i2hx;
        F4 gp = (r4 - r2) * i2hx;
        pdx4 = (r3 - r1) * i2hx;
        t14 = (kp * gp - km * gm) * i2hx;
        pdxx4 = (gp - gm) * i2hx;
        kdx4 = (kp - km) * i2hx;
        kc0v = kc; pc0v = r2;
      } else if (i == 0) {
        F4 a0 = LP(0), a1 = LP(1), a2 = LP(2), a3 = LP(3);
        F4 k0 = LK(0), k1 = LK(1), k2 = LK(2);
        F4 g0 = (4.0f * a1 - 3.0f * a0 - a2) * i2hx;
        F4 g1 = (a2 - a0) * i2hx;
        F4 g2 = (a3 - a1) * i2hx;
        pdx4 = g0;
        t14 = (4.0f * (k1 * g1) - 3.0f * (k0 * g0) - k2 * g2) * i2hx;
        pdxx4 = (4.0f * g1 - 3.0f * g0 - g2) * i2hx;
        kdx4 = (4.0f * k1 - 3.0f * k0 - k2) * i2hx;
        kc0v = k0; pc0v = a0;
      } else if (i == 1) {
        F4 a0 = LP(0), a1 = LP(1), a2 = LP(2), a3 = LP(3);
        F4 k0 = LK(0), k2 = LK(2), k1 = LK(1);
        F4 gm = (4.0f * a1 - 3.0f * a0 - a2) * i2hx;  // g(0) edge
        F4 gp = (a3 - a1) * i2hx;                      // g(2)
        pdx4 = (a2 - a0) * i2hx;
        t14 = (k2 * gp - k0 * gm) * i2hx;
        pdxx4 = (gp - gm) * i2hx;
        kdx4 = (k2 - k0) * i2hx;
        kc0v = k1; pc0v = a1;
      } else if (i == HH - 2) {  // 254
        F4 a0 = LP(HH - 4), a1 = LP(HH - 3), a2 = LP(HH - 2), a3 = LP(HH - 1);
        F4 k3 = LK(HH - 3), kcen = LK(HH - 2), kN = LK(HH - 1);
        F4 gm = (a2 - a0) * i2hx;                       // g(253)
        F4 gp = (3.0f * a3 - 4.0f * a2 + a1) * i2hx;    // g(255) edge
        pdx4 = (a3 - a1) * i2hx;
        t14 = (kN * gp - k3 * gm) * i2hx;
        pdxx4 = (gp - gm) * i2hx;
        kdx4 = (kN - k3) * i2hx;
        kc0v = kcen; pc0v = a2;
      } else {  // i == 255
        F4 a0 = LP(HH - 4), a1 = LP(HH - 3), a2 = LP(HH - 2), a3 = LP(HH - 1);
        F4 k3 = LK(HH - 3), k4 = LK(HH - 2), kN = LK(HH - 1);
        F4 gm2 = (a2 - a0) * i2hx;                      // g(253)
        F4 gm1 = (a3 - a1) * i2hx;                      // g(254)
        F4 gN = (3.0f * a3 - 4.0f * a2 + a1) * i2hx;    // g(255) edge
        pdx4 = gN;
        t14 = (3.0f * (kN * gN) - 4.0f * (k4 * gm1) + k3 * gm2) * i2hx;
        pdxx4 = (3.0f * gN - 4.0f * gm1 + gm2) * i2hx;
        kdx4 = (3.0f * kN - 4.0f * k4 + k3) * i2hx;
        kc0v = kN; pc0v = a3;
      }

      // ---- column-direction neighborhoods ----
      const int jL = (j0 >= 4) ? (j0 - 4) : 0;
      const int jR = (j0 + 4 <= WW - 4) ? (j0 + 4) : (WW - 4);
      F4 pLv = *reinterpret_cast<const F4*>(&sPc[li][jL]);
      F4 pRv = *reinterpret_cast<const F4*>(&sPc[li][jR]);
      F4 kLv = *reinterpret_cast<const F4*>(&sKc[liK][jL]);
      F4 kRv = *reinterpret_cast<const F4*>(&sKc[liK][jR]);

      float pc[12] = {pLv.x, pLv.y, pLv.z, pLv.w, pc0v.x, pc0v.y, pc0v.z, pc0v.w,
                      pRv.x, pRv.y, pRv.z, pRv.w};
      float kcA[12] = {kLv.x, kLv.y, kLv.z, kLv.w, kc0v.x, kc0v.y, kc0v.z, kc0v.w,
                       kRv.x, kRv.y, kRv.z, kRv.w};
      float pdxa[4] = {pdx4.x, pdx4.y, pdx4.z, pdx4.w};
      float t1a[4] = {t14.x, t14.y, t14.z, t14.w};
      float pdxxa[4] = {pdxx4.x, pdxx4.y, pdxx4.z, pdxx4.w};
      float kdxa[4] = {kdx4.x, kdx4.y, kdx4.z, kdx4.w};

#pragma unroll
      for (int q = 0; q < 4; ++q) {
        const int j = j0 + q;
        float pdy, t2, pdyy, kdy;
        if (j >= 2 && j <= WW - 3) {
          float gm = (pc[4 + q] - pc[2 + q]) * i2hy;
          float gp = (pc[6 + q] - pc[4 + q]) * i2hy;
          pdy = (pc[5 + q] - pc[3 + q]) * i2hy;
          t2 = (kcA[5 + q] * gp - kcA[3 + q] * gm) * i2hy;
          pdyy = (gp - gm) * i2hy;
          kdy = (kcA[5 + q] - kcA[3 + q]) * i2hy;
        } else if (j == 0) {
          float g0 = (4.0f * pc[5] - 3.0f * pc[4] - pc[6]) * i2hy;
          float g1 = (pc[6] - pc[4]) * i2hy;
          float g2 = (pc[7] - pc[5]) * i2hy;
          pdy = g0;
          t2 = (4.0f * (kcA[5] * g1) - 3.0f * (kcA[4] * g0) - kcA[6] * g2) * i2hy;
          pdyy = (4.0f * g1 - 3.0f * g0 - g2) * i2hy;
          kdy = (4.0f * kcA[5] - 3.0f * kcA[4] - kcA[6]) * i2hy;
        } else if (j == 1) {
          float gm = (4.0f * pc[5] - 3.0f * pc[4] - pc[6]) * i2hy;
          float gp = (pc[7] - pc[5]) * i2hy;
          pdy = (pc[6] - pc[4]) * i2hy;
          t2 = (kcA[6] * gp - kcA[4] * gm) * i2hy;
          pdyy = (gp - gm) * i2hy;
          kdy = (kcA[6] - kcA[4]) * i2hy;
        } else if (j == WW - 2) {
          float gm = (pc[6] - pc[4]) * i2hy;
          float gp = (3.0f * pc[7] - 4.0f * pc[6] + pc[5]) * i2hy;
          pdy = (pc[7] - pc[5]) * i2hy;
          t2 = (kcA[7] * gp - kcA[5] * gm) * i2hy;
          pdyy = (gp - gm) * i2hy;
          kdy = (kcA[7] - kcA[5]) * i2hy;
        } else {  // j == 255
          float gm2 = (pc[6] - pc[4]) * i2hy;
          float gm1 = (pc[7] - pc[5]) * i2hy;
          float gN = (3.0f * pc[7] - 4.0f * pc[6] + pc[5]) * i2hy;
          pdy = gN;
          t2 = (3.0f * (kcA[7] * gN) - 4.0f * (kcA[6] * gm1) + kcA[5] * gm2) * i2hy;
          pdyy = (3.0f * gN - 4.0f * gm1 + gm2) * i2hy;
          kdy = (3.0f * kcA[7] - 4.0f * kcA[6] + kcA[5]) * i2hy;
        }

        divka[q] = t1a[q] + t2;
        float divk2 = (pdxxa[q] + pdyy) * kcA[4 + q] + pdxa[q] * kdxa[q] + pdy * kdy;
        ma[q] = (fabsf(divka[q] - divk2) < 100.0f) ? 1.0f : 0.0f;
      }
    }

    // ---- deferred time-gradient completion + rolling update ----
#pragma unroll
    for (int q = 0; q < 4; ++q) {
      const float cT = cTa[q];
      if (t >= cmplT) {
        // finish plane t-1 (interior): p_dt = (c(t) - c(t-2))/2
        float pdt = (cT - cm2[q]) * 0.5f;
        float d = dkB[q] - pdt * Sc;
        accN += (double)(d * d * mB[q]);
        accD += (int)mB[q];
        if (t0 == 0 && t == 2) {
          // finish plane 0 (edge): p_dt = (-3c0 + 4c1 - c2)/2
          float pdt0 = (4.0f * cm1[q] - 3.0f * cm2[q] - cT) * 0.5f;
          float d0 = dkA[q] - pdt0 * Sc;
          accN += (double)(d0 * d0 * mA[q]);
          accD += (int)mA[q];
        }
      }
      if (t == TT - 1) {
        // finish plane 31 (edge): p_dt = (3c31 - 4c30 + c29)/2
        float pdtN = (3.0f * cT - 4.0f * cm1[q] + cm2[q]) * 0.5f;
        float dN = divka[q] - pdtN * Sc;
        accN += (double)(dN * dN * ma[q]);
        accD += (int)ma[q];
      }
      if (do_divk) {
        dkA[q] = dkB[q]; mA[q] = mB[q];
        dkB[q] = divka[q]; mB[q] = ma[q];
      }
      cm2[q] = cm1[q]; cm1[q] = cT;
    }

    __syncthreads();  // waves done reading buf[cur]; next-plane DMA drained
  }

  // ---- block reduction ----
  for (int off = 32; off > 0; off >>= 1) {
    accN += __shfl_down(accN, off);
    accD += __shfl_down(accD, off);
  }
  if ((tid & 63) == 0) { redN[wid] = accN; redD[wid] = accD; }
  __syncthreads();
  if (tid == 0) {
    double n = 0.0; long long dd = 0;
    for (int w = 0; w < 16; ++w) { n += redN[w]; dd += redD[w]; }
    const int slot = (b * 16 + tile) * 2 + chunk;
    ws[slot] = n;
    ws[512 + slot] = (double)dd;
  }
}

__global__ void pil_final(const double* __restrict__ ws, float* __restrict__ out) {
  __shared__ double s[16];
  const int tid = threadIdx.x;  // 512 threads: tid = b*32 + (tile*2 + chunk)
  double n = ws[tid];
  double d = ws[512 + tid];
  for (int off = 16; off > 0; off >>= 1) {
    n += __shfl_down(n, off, 32);
    d += __shfl_down(d, off, 32);
  }
  if ((tid & 31) == 0) s[tid >> 5] = n / d;
  __syncthreads();
  if (tid == 0) {
    double acc = 0.0;
    for (int bb = 0; bb < 16; ++bb) acc += s[bb];
    out[0] = (float)(acc / 16.0);
  }
}

extern "C" void kernel_launch(void* const* d_in, const int* in_sizes, int n_in,
                              void* d_out, int out_size, void* d_ws, size_t ws_size,
                              hipStream_t stream) {
  const float* p = (const float*)d_in[0];
  const float* K = (const float*)d_in[1];
  double* ws = (double*)d_ws;
  float* out = (float*)d_out;
  dim3 grid(HH / TI, 16, 2);  // (tiles per plane, batches, T-chunks)
  pil_main<<<grid, 1024, 0, stream>>>(p, K, ws);
  pil_final<<<1, 512, 0, stream>>>(ws, out);
}